// Round 4
// baseline (522.437 us; speedup 1.0000x reference)
//
#include <hip/hip_runtime.h>
#include <stdint.h>

// SNN pipeline, algebraically fused: y2 = x @ (Wh@Wp)^T + (Wh@bp + bh), then
// T-parallel LIF scan (shadowing warm-up), pool+head.
// fp32 GEMM emulated on bf16 matrix cores via hi/lo split (3 MFMA products).
// GEMM: 256x128 block tile, 32x32x16 MFMA, XOR-swizzled LDS (conflict-free).

typedef short v8s __attribute__((ext_vector_type(8)));
typedef float v16f __attribute__((ext_vector_type(16)));

#define GAS __attribute__((address_space(1)))
#define LAS __attribute__((address_space(3)))

__device__ __forceinline__ unsigned short f2bf(float f) {
  unsigned int u = __float_as_uint(f);
  u += 0x7fffu + ((u >> 16) & 1u);   // round-to-nearest-even
  return (unsigned short)(u >> 16);
}
__device__ __forceinline__ float bf2f(unsigned short h) {
  return __uint_as_float(((unsigned int)h) << 16);
}

__device__ __forceinline__ void gld_lds16(const void* g, void* l) {
  __builtin_amdgcn_global_load_lds((const GAS void*)g, (LAS void*)l, 16, 0, 0);
}

__device__ __forceinline__ void split4(const float4 x, ushort4* h, ushort4* l) {
  h->x = f2bf(x.x); l->x = f2bf(x.x - bf2f(h->x));
  h->y = f2bf(x.y); l->y = f2bf(x.y - bf2f(h->y));
  h->z = f2bf(x.z); l->z = f2bf(x.z - bf2f(h->z));
  h->w = f2bf(x.w); l->w = f2bf(x.w - bf2f(h->w));
}

// Fused weight preprocessing:
//  blocks [0,1024):    transpose+split W_proj -> WpT hi/lo
//  blocks [1024,2048): split W_hid -> Wh hi/lo
//  blocks [2048,2304): bc[g] = Wh[g,:].b_proj + b_hid[g]  (4 waves/block)
__global__ void __launch_bounds__(256) prep_kernel(
    const float* __restrict__ W_proj, const float* __restrict__ W_hid,
    const float* __restrict__ b_proj, const float* __restrict__ b_hid,
    unsigned short* __restrict__ WpTh, unsigned short* __restrict__ WpTl,
    unsigned short* __restrict__ Whh, unsigned short* __restrict__ Whl,
    float* __restrict__ bc) {
  __shared__ float t[32][33];
  const int blk = blockIdx.x, tid = threadIdx.x;
  if (blk < 1024) {
    const int tx = tid & 31, ty = tid >> 5;  // 32x8
    const int bx = blk & 31, by = blk >> 5;
    const int x = bx * 32 + tx;
    const int yb = by * 32;
#pragma unroll
    for (int j = 0; j < 4; ++j) t[ty + 8 * j][tx] = W_proj[(size_t)(yb + ty + 8 * j) * 1024 + x];
    __syncthreads();
    const int xo = yb + tx;
#pragma unroll
    for (int j = 0; j < 4; ++j) {
      const float v = t[tx][ty + 8 * j];
      const unsigned short h = f2bf(v);
      const size_t o = (size_t)(bx * 32 + ty + 8 * j) * 1024 + xo;
      WpTh[o] = h;
      WpTl[o] = f2bf(v - bf2f(h));
    }
  } else if (blk < 2048) {
    const int i = (blk - 1024) * 256 + tid;  // n4 = 262144
    float4 x = ((const float4*)W_hid)[i];
    ushort4 h, l;
    split4(x, &h, &l);
    ((ushort4*)Whh)[i] = h;
    ((ushort4*)Whl)[i] = l;
  } else {
    const int g = (blk - 2048) * 4 + (tid >> 6);
    const int lane = tid & 63;
    const float* wr = W_hid + (size_t)g * 1024;
    float s = 0.f;
#pragma unroll
    for (int i = 0; i < 16; ++i) s += wr[lane + 64 * i] * b_proj[lane + 64 * i];
#pragma unroll
    for (int off = 32; off > 0; off >>= 1) s += __shfl_down(s, off);
    if (lane == 0) bc[g] = s + b_hid[g];
  }
}

// Fused elementwise splits: blocks [0,32768) split x; rest split Wc.
__global__ void __launch_bounds__(256) split2_kernel(
    const float* __restrict__ x, unsigned short* __restrict__ Xh, unsigned short* __restrict__ Xl,
    const float* __restrict__ Wc, unsigned short* __restrict__ Wch, unsigned short* __restrict__ Wcl) {
  const int blk = blockIdx.x, tid = threadIdx.x;
  if (blk < 32768) {
    const int i = blk * 256 + tid;
    float4 v = ((const float4*)x)[i];
    ushort4 h, l;
    split4(v, &h, &l);
    ((ushort4*)Xh)[i] = h;
    ((ushort4*)Xl)[i] = l;
  } else {
    const int i = (blk - 32768) * 256 + tid;
    float4 v = ((const float4*)Wc)[i];
    ushort4 h, l;
    split4(v, &h, &l);
    ((ushort4*)Wch)[i] = h;
    ((ushort4*)Wcl)[i] = l;
  }
}

// C = A @ B^T + bias, A[M,K], B[N,K] in bf16 hi/lo; K=N=1024 fixed.
// 256x128 block tile, BK=32, 4 waves (2x2 of 128x64), 32x32x16 bf16 MFMA.
// LDS chunk XOR-swizzle: 16B chunk (r,c) lives at slot r*4 + (c^(r&3)) ->
// fragment ds_read_b128 bank starts cover all 8 positions (8-phase minimum).
__global__ void __launch_bounds__(256, 2)
gemm_bt_split(const unsigned short* __restrict__ Ah, const unsigned short* __restrict__ Al,
              const unsigned short* __restrict__ Bh, const unsigned short* __restrict__ Bl,
              const float* __restrict__ bias, float* __restrict__ outF, int M) {
  constexpr int K = 1024, N = 1024;
  __shared__ unsigned short lA[2][256 * 32];  // hi/lo 16 KB each
  __shared__ unsigned short lB[2][128 * 32];  // hi/lo 8 KB each

  const int tid = threadIdx.x;
  const int mt_total = M >> 8;
  const int band = mt_total >> 3;  // 16 for M=32768; 0 for M=1024
  int mt, nt;
  if (band) {  // XCD-aware: 8 consecutive blocks = 8 XCDs, each own mt band
    const int c = blockIdx.x & 7, idx = blockIdx.x >> 3;
    mt = c * band + (idx >> 3);
    nt = idx & 7;
  } else {
    mt = blockIdx.x >> 3;
    nt = blockIdx.x & 7;
  }
  const int m0 = mt * 256, n0 = nt * 128;

  const int lane = tid & 63, wave = tid >> 6;
  const int wm = (wave >> 1) * 128, wn = (wave & 1) * 64;
  const int ln31 = lane & 31, lh = lane >> 5;

  // staging source pointers (per-thread, swizzled chunk assignment)
  const unsigned short *pAh[4], *pAl[4], *pBh[2], *pBl[2];
#pragma unroll
  for (int q = 0; q < 4; ++q) {
    const int sg = q * 256 + tid, r = sg >> 2, cc = (sg & 3) ^ (r & 3);
    pAh[q] = Ah + (size_t)(m0 + r) * K + cc * 8;
    pAl[q] = Al + (size_t)(m0 + r) * K + cc * 8;
  }
#pragma unroll
  for (int q = 0; q < 2; ++q) {
    const int sg = q * 256 + tid, r = sg >> 2, cc = (sg & 3) ^ (r & 3);
    pBh[q] = Bh + (size_t)(n0 + r) * K + cc * 8;
    pBl[q] = Bl + (size_t)(n0 + r) * K + cc * 8;
  }

  // fragment LDS offsets (shorts); chunk for (row r, s, lh) is 2s+lh
  int offA[4][2], offB[2][2];
  const int r3 = ln31 & 3;
#pragma unroll
  for (int i = 0; i < 4; ++i)
#pragma unroll
    for (int s = 0; s < 2; ++s)
      offA[i][s] = ((wm + i * 32 + ln31) * 4 + ((2 * s + lh) ^ r3)) * 8;
#pragma unroll
  for (int j = 0; j < 2; ++j)
#pragma unroll
    for (int s = 0; s < 2; ++s)
      offB[j][s] = ((wn + j * 32 + ln31) * 4 + ((2 * s + lh) ^ r3)) * 8;

  v16f acc[4][2];
#pragma unroll
  for (int i = 0; i < 4; ++i)
#pragma unroll
    for (int j = 0; j < 2; ++j)
#pragma unroll
      for (int e = 0; e < 16; ++e) acc[i][j][e] = 0.f;

  for (int kt = 0; kt < K; kt += 32) {
#pragma unroll
    for (int q = 0; q < 4; ++q) {
      gld_lds16(pAh[q] + kt, &lA[0][(q * 256 + tid) * 8]);
      gld_lds16(pAl[q] + kt, &lA[1][(q * 256 + tid) * 8]);
    }
#pragma unroll
    for (int q = 0; q < 2; ++q) {
      gld_lds16(pBh[q] + kt, &lB[0][(q * 256 + tid) * 8]);
      gld_lds16(pBl[q] + kt, &lB[1][(q * 256 + tid) * 8]);
    }
    __syncthreads();

#pragma unroll
    for (int s = 0; s < 2; ++s) {
      v8s ah[4], al[4], bh[2], bl[2];
#pragma unroll
      for (int i = 0; i < 4; ++i) {
        ah[i] = *(const v8s*)&lA[0][offA[i][s]];
        al[i] = *(const v8s*)&lA[1][offA[i][s]];
      }
#pragma unroll
      for (int j = 0; j < 2; ++j) {
        bh[j] = *(const v8s*)&lB[0][offB[j][s]];
        bl[j] = *(const v8s*)&lB[1][offB[j][s]];
      }
#pragma unroll
      for (int i = 0; i < 4; ++i)
#pragma unroll
        for (int j = 0; j < 2; ++j)
          acc[i][j] = __builtin_amdgcn_mfma_f32_32x32x16_bf16(ah[i], bh[j], acc[i][j], 0, 0, 0);
#pragma unroll
      for (int i = 0; i < 4; ++i)
#pragma unroll
        for (int j = 0; j < 2; ++j)
          acc[i][j] = __builtin_amdgcn_mfma_f32_32x32x16_bf16(ah[i], bl[j], acc[i][j], 0, 0, 0);
#pragma unroll
      for (int i = 0; i < 4; ++i)
#pragma unroll
        for (int j = 0; j < 2; ++j)
          acc[i][j] = __builtin_amdgcn_mfma_f32_32x32x16_bf16(al[i], bh[j], acc[i][j], 0, 0, 0);
    }
    __syncthreads();
  }

  // epilogue: 32x32 C/D: col=lane&31, row=(reg&3)+8*(reg>>2)+4*(lane>>5)
#pragma unroll
  for (int i = 0; i < 4; ++i)
#pragma unroll
    for (int j = 0; j < 2; ++j) {
      const int gn = n0 + wn + j * 32 + ln31;
      const float bv = bias ? bias[gn] : 0.f;
#pragma unroll
      for (int reg = 0; reg < 16; ++reg) {
        const int gm = m0 + wm + i * 32 + (reg & 3) + 8 * (reg >> 2) + 4 * lh;
        outF[(size_t)gm * N + gn] = acc[i][j][reg] + bv;
      }
    }
}

// T-parallel LIF: 8 chunks of 128 steps, 64-step shadowing warm-up (state
// contracts x0.5/step -> bit-exact convergence before the chunk starts).
__global__ void __launch_bounds__(256) lif_part_kernel(const float* __restrict__ y2,
                                                       float* __restrict__ part) {
  const int idx = blockIdx.x * 256 + threadIdx.x;  // chunk*32768 + ch
  const int ch = idx & 32767, chunk = idx >> 15;
  const float* p = y2 + ((size_t)(ch >> 10) << 20) + (ch & 1023);
  const int t0 = chunk << 7;
  float v = 0.f;
  if (chunk) {  // uniform per wave (32768 % 64 == 0)
    const float* pw = p + (size_t)(t0 - 64) * 1024;
    for (int b = 0; b < 64; b += 16) {
      float x[16];
#pragma unroll
      for (int i = 0; i < 16; ++i) x[i] = pw[(size_t)(b + i) * 1024];
#pragma unroll
      for (int i = 0; i < 16; ++i) {
        v += (x[i] - v) * 0.5f;
        if (v >= 1.0f) v -= 1.0f;
      }
    }
  }
  float cnt = 0.f;
  const float* pm = p + (size_t)t0 * 1024;
  for (int b = 0; b < 128; b += 16) {
    float x[16];
#pragma unroll
    for (int i = 0; i < 16; ++i) x[i] = pm[(size_t)(b + i) * 1024];
#pragma unroll
    for (int i = 0; i < 16; ++i) {
      v += (x[i] - v) * 0.5f;              // exact reference op order
      float s = (v >= 1.0f) ? 1.0f : 0.0f;
      cnt += s;
      v -= s;
    }
  }
  part[idx] = cnt;
}

// out[b,o] = (sum_c part[c][b,:]).W_out[o,:]/1024 + b_out[o]; one wave each.
// part holds integer spike counts -> cross-chunk sum exact in any order.
__global__ void __launch_bounds__(64) head_kernel(const float* __restrict__ part,
                                                  const float* __restrict__ W_out,
                                                  const float* __restrict__ b_out,
                                                  float* __restrict__ out) {
  int blk = blockIdx.x;          // 0..319
  int b = blk / 10, o = blk % 10;
  int lane = threadIdx.x;
  const float* wr = W_out + o * 1024;
  float s = 0.f;
#pragma unroll
  for (int i = 0; i < 16; ++i) {
    const int ch = b * 1024 + lane + 64 * i;
    float p = 0.f;
#pragma unroll
    for (int c = 0; c < 8; ++c) p += part[c * 32768 + ch];
    s += p * wr[lane + 64 * i];
  }
#pragma unroll
  for (int off = 32; off > 0; off >>= 1) s += __shfl_down(s, off);
  if (lane == 0) out[b * 10 + o] = s * (1.0f / 1024.0f) + b_out[o];
}

extern "C" void kernel_launch(void* const* d_in, const int* in_sizes, int n_in,
                              void* d_out, int out_size, void* d_ws, size_t ws_size,
                              hipStream_t stream) {
  const float* x      = (const float*)d_in[0];
  const float* W_proj = (const float*)d_in[1];
  const float* b_proj = (const float*)d_in[2];
  const float* W_hid  = (const float*)d_in[3];
  const float* b_hid  = (const float*)d_in[4];
  const float* W_out  = (const float*)d_in[5];
  const float* b_out  = (const float*)d_in[6];
  float* out = (float*)d_out;

  const int M = 32768;  // B*T

  // Workspace (~277 MB):
  //   [0, 64M)     Xh   (dead after main GEMM; `part` aliases its start)
  //   [64M, 128M)  Xl
  //   [128M, 256M) Y2 fp32 (Wc fp32 at its start; dead once split)
  //   [256M, ...)  WpT/Wc hi+lo (aliased), Wh hi/lo, bc
  char* ws = (char*)d_ws;
  unsigned short* Xh   = (unsigned short*)(ws);
  unsigned short* Xl   = (unsigned short*)(ws + 67108864);
  float*          part = (float*)(ws);                      // 1 MB, aliases Xh
  float*          Y2   = (float*)(ws + 134217728);
  float*          Wc   = (float*)(ws + 134217728);          // aliases Y2 start
  char* base = ws + 268435456;
  unsigned short* WpTh = (unsigned short*)(base);            // reused as Wch
  unsigned short* WpTl = (unsigned short*)(base + 2097152);  // reused as Wcl
  unsigned short* Whh  = (unsigned short*)(base + 4194304);
  unsigned short* Whl  = (unsigned short*)(base + 6291456);
  float*           bc  = (float*)(base + 8388608);
  unsigned short* Wch  = WpTh;  // WpT dead after Wc GEMM
  unsigned short* Wcl  = WpTl;

  prep_kernel<<<2304, 256, 0, stream>>>(W_proj, W_hid, b_proj, b_hid,
                                        WpTh, WpTl, Whh, Whl, bc);
  // Wc[g,d] = sum_h Wh[g,h] * WpT[d,h]
  gemm_bt_split<<<32, 256, 0, stream>>>(Whh, Whl, WpTh, WpTl, nullptr, Wc, 1024);
  split2_kernel<<<33792, 256, 0, stream>>>(x, Xh, Xl, Wc, Wch, Wcl);
  gemm_bt_split<<<1024, 256, 0, stream>>>(Xh, Xl, Wch, Wcl, bc, Y2, M);
  lif_part_kernel<<<1024, 256, 0, stream>>>(Y2, part);
  head_kernel<<<320, 64, 0, stream>>>(part, W_out, b_out, out);
}

// Round 5
// 477.678 us; speedup vs baseline: 1.0937x; 1.0937x over previous
//
#include <hip/hip_runtime.h>
#include <stdint.h>

// SNN pipeline, algebraically fused: y2 = x @ (Wh@Wp)^T + (Wh@bp + bh), then
// T-parallel LIF scan (shadowing warm-up), pool+head.
// fp32 GEMM on bf16 matrix cores via hi/lo split (3 MFMA products).
// Main GEMM reads fp32 X directly and splits in-register during LDS staging
// (same HBM bytes as pre-split, deletes the standalone 256MB-traffic split).
// 128x128 tile / 16x16x32 MFMA / natural layout: proven best (r2: 206us).

typedef short v8s __attribute__((ext_vector_type(8)));
typedef float v4f __attribute__((ext_vector_type(4)));

#define GAS __attribute__((address_space(1)))
#define LAS __attribute__((address_space(3)))

__device__ __forceinline__ unsigned short f2bf(float f) {
  unsigned int u = __float_as_uint(f);
  u += 0x7fffu + ((u >> 16) & 1u);   // round-to-nearest-even
  return (unsigned short)(u >> 16);
}
__device__ __forceinline__ float bf2f(unsigned short h) {
  return __uint_as_float(((unsigned int)h) << 16);
}

__device__ __forceinline__ void gld_lds16(const void* g, void* l) {
  __builtin_amdgcn_global_load_lds((const GAS void*)g, (LAS void*)l, 16, 0, 0);
}

__device__ __forceinline__ void split4(const float4 x, ushort4* h, ushort4* l) {
  h->x = f2bf(x.x); l->x = f2bf(x.x - bf2f(h->x));
  h->y = f2bf(x.y); l->y = f2bf(x.y - bf2f(h->y));
  h->z = f2bf(x.z); l->z = f2bf(x.z - bf2f(h->z));
  h->w = f2bf(x.w); l->w = f2bf(x.w - bf2f(h->w));
}

// 8 floats -> 8 bf16 hi + 8 bf16 lo packed for one ds_write_b128 each.
__device__ __forceinline__ void split8(const float4 a, const float4 b, v8s* hi, v8s* lo) {
  const float f[8] = {a.x, a.y, a.z, a.w, b.x, b.y, b.z, b.w};
  v8s h, l;
#pragma unroll
  for (int i = 0; i < 8; ++i) {
    const unsigned short hh = f2bf(f[i]);
    ((unsigned short*)&h)[i] = hh;
    ((unsigned short*)&l)[i] = f2bf(f[i] - bf2f(hh));
  }
  *hi = h; *lo = l;
}

// Fused weight preprocessing:
//  blocks [0,1024):    transpose+split W_proj -> WpT hi/lo
//  blocks [1024,2048): split W_hid -> Wh hi/lo
//  blocks [2048,2304): bc[g] = Wh[g,:].b_proj + b_hid[g]  (4 waves/block)
__global__ void __launch_bounds__(256) prep_kernel(
    const float* __restrict__ W_proj, const float* __restrict__ W_hid,
    const float* __restrict__ b_proj, const float* __restrict__ b_hid,
    unsigned short* __restrict__ WpTh, unsigned short* __restrict__ WpTl,
    unsigned short* __restrict__ Whh, unsigned short* __restrict__ Whl,
    float* __restrict__ bc) {
  __shared__ float t[32][33];
  const int blk = blockIdx.x, tid = threadIdx.x;
  if (blk < 1024) {
    const int tx = tid & 31, ty = tid >> 5;  // 32x8
    const int bx = blk & 31, by = blk >> 5;
    const int x = bx * 32 + tx;
    const int yb = by * 32;
#pragma unroll
    for (int j = 0; j < 4; ++j) t[ty + 8 * j][tx] = W_proj[(size_t)(yb + ty + 8 * j) * 1024 + x];
    __syncthreads();
    const int xo = yb + tx;
#pragma unroll
    for (int j = 0; j < 4; ++j) {
      const float v = t[tx][ty + 8 * j];
      const unsigned short h = f2bf(v);
      const size_t o = (size_t)(bx * 32 + ty + 8 * j) * 1024 + xo;
      WpTh[o] = h;
      WpTl[o] = f2bf(v - bf2f(h));
    }
  } else if (blk < 2048) {
    const int i = (blk - 1024) * 256 + tid;  // n4 = 262144
    float4 x = ((const float4*)W_hid)[i];
    ushort4 h, l;
    split4(x, &h, &l);
    ((ushort4*)Whh)[i] = h;
    ((ushort4*)Whl)[i] = l;
  } else {
    const int g = (blk - 2048) * 4 + (tid >> 6);
    const int lane = tid & 63;
    const float* wr = W_hid + (size_t)g * 1024;
    float s = 0.f;
#pragma unroll
    for (int i = 0; i < 16; ++i) s += wr[lane + 64 * i] * b_proj[lane + 64 * i];
#pragma unroll
    for (int off = 32; off > 0; off >>= 1) s += __shfl_down(s, off);
    if (lane == 0) bc[g] = s + b_hid[g];
  }
}

// Small weight GEMM: C = A @ B^T, A/B pre-split bf16 hi/lo, M=N=K=1024.
// 128x128 tile, round-2 structure; epilogue writes C re-split to bf16 hi/lo.
__global__ void __launch_bounds__(256, 2)
gemm_w(const unsigned short* __restrict__ Ah, const unsigned short* __restrict__ Al,
       const unsigned short* __restrict__ Bh, const unsigned short* __restrict__ Bl,
       unsigned short* __restrict__ outH, unsigned short* __restrict__ outL) {
  constexpr int K = 1024, N = 1024;
  __shared__ unsigned short lA[2][128 * 32];
  __shared__ unsigned short lB[2][128 * 32];

  const int tid = threadIdx.x;
  const int mt = blockIdx.x & 7, nt = blockIdx.x >> 3;  // 8x8 grid
  const int m0 = mt * 128, n0 = nt * 128;

  const int lane = tid & 63, wave = tid >> 6;
  const int wm = (wave >> 1) * 64, wn = (wave & 1) * 64;
  const int quad = lane >> 4, r = lane & 15;
  const int srow = tid >> 2, scol = (tid & 3) * 8;

  v4f acc[4][4];
#pragma unroll
  for (int i = 0; i < 4; ++i)
#pragma unroll
    for (int j = 0; j < 4; ++j) acc[i][j] = v4f{0.f, 0.f, 0.f, 0.f};

  const unsigned short* gAh = Ah + (size_t)(m0 + srow) * K + scol;
  const unsigned short* gAl = Al + (size_t)(m0 + srow) * K + scol;
  const unsigned short* gBh = Bh + (size_t)(n0 + srow) * K + scol;
  const unsigned short* gBl = Bl + (size_t)(n0 + srow) * K + scol;

  for (int kt = 0; kt < K; kt += 32) {
    gld_lds16(gAh + kt,          &lA[0][tid * 8]);
    gld_lds16(gAh + kt + 64 * K, &lA[0][tid * 8 + 64 * 32]);
    gld_lds16(gAl + kt,          &lA[1][tid * 8]);
    gld_lds16(gAl + kt + 64 * K, &lA[1][tid * 8 + 64 * 32]);
    gld_lds16(gBh + kt,          &lB[0][tid * 8]);
    gld_lds16(gBh + kt + 64 * K, &lB[0][tid * 8 + 64 * 32]);
    gld_lds16(gBl + kt,          &lB[1][tid * 8]);
    gld_lds16(gBl + kt + 64 * K, &lB[1][tid * 8 + 64 * 32]);
    __syncthreads();

    v8s ah[4], al[4], bh[4], bl[4];
#pragma unroll
    for (int i = 0; i < 4; ++i) {
      ah[i] = *(const v8s*)&lA[0][(wm + i * 16 + r) * 32 + quad * 8];
      al[i] = *(const v8s*)&lA[1][(wm + i * 16 + r) * 32 + quad * 8];
      bh[i] = *(const v8s*)&lB[0][(wn + i * 16 + r) * 32 + quad * 8];
      bl[i] = *(const v8s*)&lB[1][(wn + i * 16 + r) * 32 + quad * 8];
    }
#pragma unroll
    for (int i = 0; i < 4; ++i)
#pragma unroll
      for (int j = 0; j < 4; ++j) {
        acc[i][j] = __builtin_amdgcn_mfma_f32_16x16x32_bf16(ah[i], bh[j], acc[i][j], 0, 0, 0);
        acc[i][j] = __builtin_amdgcn_mfma_f32_16x16x32_bf16(ah[i], bl[j], acc[i][j], 0, 0, 0);
        acc[i][j] = __builtin_amdgcn_mfma_f32_16x16x32_bf16(al[i], bh[j], acc[i][j], 0, 0, 0);
      }
    __syncthreads();
  }

#pragma unroll
  for (int i = 0; i < 4; ++i)
#pragma unroll
    for (int j = 0; j < 4; ++j) {
      const int gn = n0 + wn + j * 16 + r;
#pragma unroll
      for (int q2 = 0; q2 < 4; ++q2) {
        const int gm = m0 + wm + i * 16 + quad * 4 + q2;
        const float y = acc[i][j][q2];
        const unsigned short h = f2bf(y);
        const size_t o = (size_t)gm * N + gn;
        outH[o] = h;
        outL[o] = f2bf(y - bf2f(h));
      }
    }
}

// Main GEMM: Y2 = X(fp32) @ Wc^T + bc. X split to bf16 hi/lo in-register
// during staging (ds_write_b128, bank-minimal); Wc pre-split via gld_lds.
// 128x128 tile, BK=32, 4 waves 2x2 of 64x64, 16x16x32 bf16 MFMA, 3 products.
// XCD swizzle: 8 consecutive blocks share one A-band across the 8 XCDs.
__global__ void __launch_bounds__(256, 4)
gemm_xf32(const float* __restrict__ X,
          const unsigned short* __restrict__ Bh, const unsigned short* __restrict__ Bl,
          const float* __restrict__ bias, float* __restrict__ outF, int M) {
  constexpr int K = 1024, N = 1024;
  __shared__ unsigned short lA[2][128 * 32];  // hi/lo 8 KB each
  __shared__ unsigned short lB[2][128 * 32];

  const int tid = threadIdx.x;
  const int band = (M >> 7) >> 3;            // 32 for M=32768
  const int c = blockIdx.x & 7, idx = blockIdx.x >> 3;
  const int mt = c * band + (idx >> 3), nt = idx & 7;
  const int m0 = mt * 128, n0 = nt * 128;

  const int lane = tid & 63, wave = tid >> 6;
  const int wm = (wave >> 1) * 64, wn = (wave & 1) * 64;
  const int quad = lane >> 4, r = lane & 15;
  const int srow = tid >> 2, scol = (tid & 3) * 8;

  v4f acc[4][4];
#pragma unroll
  for (int i = 0; i < 4; ++i)
#pragma unroll
    for (int j = 0; j < 4; ++j) acc[i][j] = v4f{0.f, 0.f, 0.f, 0.f};

  const float* gA0 = X + (size_t)(m0 + srow) * K + scol;       // rows 0..63
  const float* gA1 = gA0 + (size_t)64 * K;                      // rows 64..127
  const unsigned short* gBh = Bh + (size_t)(n0 + srow) * K + scol;
  const unsigned short* gBl = Bl + (size_t)(n0 + srow) * K + scol;

  for (int kt = 0; kt < K; kt += 32) {
    // B: async global->LDS (L2-resident, 4MB total)
    gld_lds16(gBh + kt,          &lB[0][tid * 8]);
    gld_lds16(gBh + kt + 64 * K, &lB[0][tid * 8 + 64 * 32]);
    gld_lds16(gBl + kt,          &lB[1][tid * 8]);
    gld_lds16(gBl + kt + 64 * K, &lB[1][tid * 8 + 64 * 32]);
    // A: fp32 load -> hi/lo split -> ds_write_b128 (banks: 8-phase minimal)
    const float4 f0 = *(const float4*)(gA0 + kt);
    const float4 f1 = *(const float4*)(gA0 + kt + 4);
    const float4 f2 = *(const float4*)(gA1 + kt);
    const float4 f3 = *(const float4*)(gA1 + kt + 4);
    v8s h0, l0, h1, l1;
    split8(f0, f1, &h0, &l0);
    split8(f2, f3, &h1, &l1);
    *(v8s*)&lA[0][srow * 32 + scol] = h0;
    *(v8s*)&lA[1][srow * 32 + scol] = l0;
    *(v8s*)&lA[0][(srow + 64) * 32 + scol] = h1;
    *(v8s*)&lA[1][(srow + 64) * 32 + scol] = l1;
    __syncthreads();

    v8s ah[4], al[4], bh[4], bl[4];
#pragma unroll
    for (int i = 0; i < 4; ++i) {
      ah[i] = *(const v8s*)&lA[0][(wm + i * 16 + r) * 32 + quad * 8];
      al[i] = *(const v8s*)&lA[1][(wm + i * 16 + r) * 32 + quad * 8];
      bh[i] = *(const v8s*)&lB[0][(wn + i * 16 + r) * 32 + quad * 8];
      bl[i] = *(const v8s*)&lB[1][(wn + i * 16 + r) * 32 + quad * 8];
    }
#pragma unroll
    for (int i = 0; i < 4; ++i)
#pragma unroll
      for (int j = 0; j < 4; ++j) {
        acc[i][j] = __builtin_amdgcn_mfma_f32_16x16x32_bf16(ah[i], bh[j], acc[i][j], 0, 0, 0);
        acc[i][j] = __builtin_amdgcn_mfma_f32_16x16x32_bf16(ah[i], bl[j], acc[i][j], 0, 0, 0);
        acc[i][j] = __builtin_amdgcn_mfma_f32_16x16x32_bf16(al[i], bh[j], acc[i][j], 0, 0, 0);
      }
    __syncthreads();
  }

  // epilogue: C[m = quad*4+reg][n = lane&15] (verified gfx950 16x16 C/D layout)
#pragma unroll
  for (int i = 0; i < 4; ++i)
#pragma unroll
    for (int j = 0; j < 4; ++j) {
      const int gn = n0 + wn + j * 16 + r;
      const float bv = bias[gn];
#pragma unroll
      for (int q2 = 0; q2 < 4; ++q2) {
        const int gm = m0 + wm + i * 16 + quad * 4 + q2;
        outF[(size_t)gm * N + gn] = acc[i][j][q2] + bv;
      }
    }
}

// T-parallel LIF: 8 chunks of 128 steps, 64-step shadowing warm-up (state
// contracts x0.5/step -> bit-exact convergence before the chunk starts).
__global__ void __launch_bounds__(256) lif_part_kernel(const float* __restrict__ y2,
                                                       float* __restrict__ part) {
  const int idx = blockIdx.x * 256 + threadIdx.x;  // chunk*32768 + ch
  const int ch = idx & 32767, chunk = idx >> 15;
  const float* p = y2 + ((size_t)(ch >> 10) << 20) + (ch & 1023);
  const int t0 = chunk << 7;
  float v = 0.f;
  if (chunk) {  // uniform per wave (32768 % 64 == 0)
    const float* pw = p + (size_t)(t0 - 64) * 1024;
    for (int b = 0; b < 64; b += 16) {
      float x[16];
#pragma unroll
      for (int i = 0; i < 16; ++i) x[i] = pw[(size_t)(b + i) * 1024];
#pragma unroll
      for (int i = 0; i < 16; ++i) {
        v += (x[i] - v) * 0.5f;
        if (v >= 1.0f) v -= 1.0f;
      }
    }
  }
  float cnt = 0.f;
  const float* pm = p + (size_t)t0 * 1024;
  for (int b = 0; b < 128; b += 16) {
    float x[16];
#pragma unroll
    for (int i = 0; i < 16; ++i) x[i] = pm[(size_t)(b + i) * 1024];
#pragma unroll
    for (int i = 0; i < 16; ++i) {
      v += (x[i] - v) * 0.5f;              // exact reference op order
      float s = (v >= 1.0f) ? 1.0f : 0.0f;
      cnt += s;
      v -= s;
    }
  }
  part[idx] = cnt;
}

// out[b,o] = (sum_c part[c][b,:]).W_out[o,:]/1024 + b_out[o]; one wave each.
// part holds integer spike counts -> cross-chunk sum exact in any order.
__global__ void __launch_bounds__(64) head_kernel(const float* __restrict__ part,
                                                  const float* __restrict__ W_out,
                                                  const float* __restrict__ b_out,
                                                  float* __restrict__ out) {
  int blk = blockIdx.x;          // 0..319
  int b = blk / 10, o = blk % 10;
  int lane = threadIdx.x;
  const float* wr = W_out + o * 1024;
  float s = 0.f;
#pragma unroll
  for (int i = 0; i < 16; ++i) {
    const int ch = b * 1024 + lane + 64 * i;
    float p = 0.f;
#pragma unroll
    for (int c = 0; c < 8; ++c) p += part[c * 32768 + ch];
    s += p * wr[lane + 64 * i];
  }
#pragma unroll
  for (int off = 32; off > 0; off >>= 1) s += __shfl_down(s, off);
  if (lane == 0) out[b * 10 + o] = s * (1.0f / 1024.0f) + b_out[o];
}

extern "C" void kernel_launch(void* const* d_in, const int* in_sizes, int n_in,
                              void* d_out, int out_size, void* d_ws, size_t ws_size,
                              hipStream_t stream) {
  const float* x      = (const float*)d_in[0];
  const float* W_proj = (const float*)d_in[1];
  const float* b_proj = (const float*)d_in[2];
  const float* W_hid  = (const float*)d_in[3];
  const float* b_hid  = (const float*)d_in[4];
  const float* W_out  = (const float*)d_in[5];
  const float* b_out  = (const float*)d_in[6];
  float* out = (float*)d_out;

  const int M = 32768;  // B*T

  // Workspace (~141 MB): Y2 fp32 [128MB] | WpT hi/lo | Wh hi/lo | Wc hi/lo |
  // bc | part
  char* ws = (char*)d_ws;
  float*          Y2   = (float*)(ws);
  char* base = ws + 134217728;
  unsigned short* WpTh = (unsigned short*)(base);
  unsigned short* WpTl = (unsigned short*)(base + 2097152);
  unsigned short* Whh  = (unsigned short*)(base + 4194304);
  unsigned short* Whl  = (unsigned short*)(base + 6291456);
  unsigned short* Wch  = (unsigned short*)(base + 8388608);
  unsigned short* Wcl  = (unsigned short*)(base + 10485760);
  float*           bc  = (float*)(base + 12582912);
  float*          part = (float*)(base + 12582912 + 65536);

  prep_kernel<<<2304, 256, 0, stream>>>(W_proj, W_hid, b_proj, b_hid,
                                        WpTh, WpTl, Whh, Whl, bc);
  // Wc[g,d] = sum_h Wh[g,h] * WpT[d,h], written pre-split hi/lo
  gemm_w<<<64, 256, 0, stream>>>(Whh, Whl, WpTh, WpTl, Wch, Wcl);
  gemm_xf32<<<2048, 256, 0, stream>>>(x, Wch, Wcl, bc, Y2, M);
  lif_part_kernel<<<1024, 256, 0, stream>>>(Y2, part);
  head_kernel<<<320, 64, 0, stream>>>(part, W_out, b_out, out);
}

// Round 6
// 475.891 us; speedup vs baseline: 1.0978x; 1.0038x over previous
//
#include <hip/hip_runtime.h>
#include <stdint.h>

// SNN pipeline, algebraically fused: y2 = x @ (Wh@Wp)^T + (Wh@bp + bh), then
// T-parallel LIF scan (shadowing warm-up), pool+head.
// fp32 GEMM on bf16 matrix cores via hi/lo split (3 MFMA products).
// r6: GEMM restored to r2-exact structure (pre-split A, async gld_lds staging,
// 128x128 / 16x16x32 / natural layout -- measured 206us, ~1000 TF effective).
// X hi/lo split folded into prep_kernel's grid (no standalone launch).

typedef short v8s __attribute__((ext_vector_type(8)));
typedef float v4f __attribute__((ext_vector_type(4)));

#define GAS __attribute__((address_space(1)))
#define LAS __attribute__((address_space(3)))

__device__ __forceinline__ unsigned short f2bf(float f) {
  unsigned int u = __float_as_uint(f);
  u += 0x7fffu + ((u >> 16) & 1u);   // round-to-nearest-even
  return (unsigned short)(u >> 16);
}
__device__ __forceinline__ float bf2f(unsigned short h) {
  return __uint_as_float(((unsigned int)h) << 16);
}

__device__ __forceinline__ void gld_lds16(const void* g, void* l) {
  __builtin_amdgcn_global_load_lds((const GAS void*)g, (LAS void*)l, 16, 0, 0);
}

__device__ __forceinline__ void split4(const float4 x, ushort4* h, ushort4* l) {
  h->x = f2bf(x.x); l->x = f2bf(x.x - bf2f(h->x));
  h->y = f2bf(x.y); l->y = f2bf(x.y - bf2f(h->y));
  h->z = f2bf(x.z); l->z = f2bf(x.z - bf2f(h->z));
  h->w = f2bf(x.w); l->w = f2bf(x.w - bf2f(h->w));
}

// Fused preprocessing (one launch, independent block ranges):
//  [0, 32768):      split x -> Xh/Xl            (256 MB traffic, HBM-bound)
//  [32768, 33792):  transpose+split W_proj -> WpT hi/lo
//  [33792, 34816):  split W_hid -> Wh hi/lo
//  [34816, 35072):  bc[g] = Wh[g,:].b_proj + b_hid[g]  (4 waves/block)
__global__ void __launch_bounds__(256) prep_kernel(
    const float* __restrict__ x,
    const float* __restrict__ W_proj, const float* __restrict__ W_hid,
    const float* __restrict__ b_proj, const float* __restrict__ b_hid,
    unsigned short* __restrict__ Xh, unsigned short* __restrict__ Xl,
    unsigned short* __restrict__ WpTh, unsigned short* __restrict__ WpTl,
    unsigned short* __restrict__ Whh, unsigned short* __restrict__ Whl,
    float* __restrict__ bc) {
  __shared__ float t[32][33];
  const int blk = blockIdx.x, tid = threadIdx.x;
  if (blk < 32768) {
    const int i = blk * 256 + tid;           // 8388608 float4 = 32M floats
    float4 v = ((const float4*)x)[i];
    ushort4 h, l;
    split4(v, &h, &l);
    ((ushort4*)Xh)[i] = h;
    ((ushort4*)Xl)[i] = l;
  } else if (blk < 33792) {
    const int b2 = blk - 32768;
    const int tx = tid & 31, ty = tid >> 5;  // 32x8
    const int bx = b2 & 31, by = b2 >> 5;
    const int xc = bx * 32 + tx;
    const int yb = by * 32;
#pragma unroll
    for (int j = 0; j < 4; ++j) t[ty + 8 * j][tx] = W_proj[(size_t)(yb + ty + 8 * j) * 1024 + xc];
    __syncthreads();
    const int xo = yb + tx;
#pragma unroll
    for (int j = 0; j < 4; ++j) {
      const float v = t[tx][ty + 8 * j];
      const unsigned short h = f2bf(v);
      const size_t o = (size_t)(bx * 32 + ty + 8 * j) * 1024 + xo;
      WpTh[o] = h;
      WpTl[o] = f2bf(v - bf2f(h));
    }
  } else if (blk < 34816) {
    const int i = (blk - 33792) * 256 + tid; // 262144 float4 = 1M floats
    float4 v = ((const float4*)W_hid)[i];
    ushort4 h, l;
    split4(v, &h, &l);
    ((ushort4*)Whh)[i] = h;
    ((ushort4*)Whl)[i] = l;
  } else {
    const int g = (blk - 34816) * 4 + (tid >> 6);
    const int lane = tid & 63;
    const float* wr = W_hid + (size_t)g * 1024;
    float s = 0.f;
#pragma unroll
    for (int i = 0; i < 16; ++i) s += wr[lane + 64 * i] * b_proj[lane + 64 * i];
#pragma unroll
    for (int off = 32; off > 0; off >>= 1) s += __shfl_down(s, off);
    if (lane == 0) bc[g] = s + b_hid[g];
  }
}

// Small weight GEMM: C = A @ B^T, A/B pre-split bf16 hi/lo, M=N=K=1024.
// 128x128 tile; epilogue writes C re-split to bf16 hi/lo (feeds main GEMM).
__global__ void __launch_bounds__(256, 2)
gemm_w(const unsigned short* __restrict__ Ah, const unsigned short* __restrict__ Al,
       const unsigned short* __restrict__ Bh, const unsigned short* __restrict__ Bl,
       unsigned short* __restrict__ outH, unsigned short* __restrict__ outL) {
  constexpr int K = 1024, N = 1024;
  __shared__ unsigned short lA[2][128 * 32];
  __shared__ unsigned short lB[2][128 * 32];

  const int tid = threadIdx.x;
  const int mt = blockIdx.x & 7, nt = blockIdx.x >> 3;  // 8x8 grid
  const int m0 = mt * 128, n0 = nt * 128;

  const int lane = tid & 63, wave = tid >> 6;
  const int wm = (wave >> 1) * 64, wn = (wave & 1) * 64;
  const int quad = lane >> 4, r = lane & 15;
  const int srow = tid >> 2, scol = (tid & 3) * 8;

  v4f acc[4][4];
#pragma unroll
  for (int i = 0; i < 4; ++i)
#pragma unroll
    for (int j = 0; j < 4; ++j) acc[i][j] = v4f{0.f, 0.f, 0.f, 0.f};

  const unsigned short* gAh = Ah + (size_t)(m0 + srow) * K + scol;
  const unsigned short* gAl = Al + (size_t)(m0 + srow) * K + scol;
  const unsigned short* gBh = Bh + (size_t)(n0 + srow) * K + scol;
  const unsigned short* gBl = Bl + (size_t)(n0 + srow) * K + scol;

  for (int kt = 0; kt < K; kt += 32) {
    gld_lds16(gAh + kt,          &lA[0][tid * 8]);
    gld_lds16(gAh + kt + 64 * K, &lA[0][tid * 8 + 64 * 32]);
    gld_lds16(gAl + kt,          &lA[1][tid * 8]);
    gld_lds16(gAl + kt + 64 * K, &lA[1][tid * 8 + 64 * 32]);
    gld_lds16(gBh + kt,          &lB[0][tid * 8]);
    gld_lds16(gBh + kt + 64 * K, &lB[0][tid * 8 + 64 * 32]);
    gld_lds16(gBl + kt,          &lB[1][tid * 8]);
    gld_lds16(gBl + kt + 64 * K, &lB[1][tid * 8 + 64 * 32]);
    __syncthreads();

    v8s ah[4], al[4], bh[4], bl[4];
#pragma unroll
    for (int i = 0; i < 4; ++i) {
      ah[i] = *(const v8s*)&lA[0][(wm + i * 16 + r) * 32 + quad * 8];
      al[i] = *(const v8s*)&lA[1][(wm + i * 16 + r) * 32 + quad * 8];
      bh[i] = *(const v8s*)&lB[0][(wn + i * 16 + r) * 32 + quad * 8];
      bl[i] = *(const v8s*)&lB[1][(wn + i * 16 + r) * 32 + quad * 8];
    }
#pragma unroll
    for (int i = 0; i < 4; ++i)
#pragma unroll
      for (int j = 0; j < 4; ++j) {
        acc[i][j] = __builtin_amdgcn_mfma_f32_16x16x32_bf16(ah[i], bh[j], acc[i][j], 0, 0, 0);
        acc[i][j] = __builtin_amdgcn_mfma_f32_16x16x32_bf16(ah[i], bl[j], acc[i][j], 0, 0, 0);
        acc[i][j] = __builtin_amdgcn_mfma_f32_16x16x32_bf16(al[i], bh[j], acc[i][j], 0, 0, 0);
      }
    __syncthreads();
  }

#pragma unroll
  for (int i = 0; i < 4; ++i)
#pragma unroll
    for (int j = 0; j < 4; ++j) {
      const int gn = n0 + wn + j * 16 + r;
#pragma unroll
      for (int q2 = 0; q2 < 4; ++q2) {
        const int gm = m0 + wm + i * 16 + quad * 4 + q2;
        const float y = acc[i][j][q2];
        const unsigned short h = f2bf(y);
        const size_t o = (size_t)gm * N + gn;
        outH[o] = h;
        outL[o] = f2bf(y - bf2f(h));
      }
    }
}

// Main GEMM (r2-exact structure, measured 206us): Y2 = Xsplit @ Wc^T + bc.
// A,B pre-split bf16 hi/lo, all staging via async gld_lds. 128x128 tile,
// BK=32, 4 waves 2x2 of 64x64, 16x16x32 MFMA, 3 products. XCD swizzle:
// 8 consecutive blocks share one A-band across the 8 XCDs.
__global__ void __launch_bounds__(256, 2)
gemm_main(const unsigned short* __restrict__ Ah, const unsigned short* __restrict__ Al,
          const unsigned short* __restrict__ Bh, const unsigned short* __restrict__ Bl,
          const float* __restrict__ bias, float* __restrict__ outF, int M) {
  constexpr int K = 1024, N = 1024;
  __shared__ unsigned short lA[2][128 * 32];
  __shared__ unsigned short lB[2][128 * 32];

  const int tid = threadIdx.x;
  const int band = (M >> 7) >> 3;            // 32 for M=32768
  const int c = blockIdx.x & 7, idx = blockIdx.x >> 3;
  const int mt = c * band + (idx >> 3), nt = idx & 7;
  const int m0 = mt * 128, n0 = nt * 128;

  const int lane = tid & 63, wave = tid >> 6;
  const int wm = (wave >> 1) * 64, wn = (wave & 1) * 64;
  const int quad = lane >> 4, r = lane & 15;
  const int srow = tid >> 2, scol = (tid & 3) * 8;

  v4f acc[4][4];
#pragma unroll
  for (int i = 0; i < 4; ++i)
#pragma unroll
    for (int j = 0; j < 4; ++j) acc[i][j] = v4f{0.f, 0.f, 0.f, 0.f};

  const unsigned short* gAh = Ah + (size_t)(m0 + srow) * K + scol;
  const unsigned short* gAl = Al + (size_t)(m0 + srow) * K + scol;
  const unsigned short* gBh = Bh + (size_t)(n0 + srow) * K + scol;
  const unsigned short* gBl = Bl + (size_t)(n0 + srow) * K + scol;

  for (int kt = 0; kt < K; kt += 32) {
    gld_lds16(gAh + kt,          &lA[0][tid * 8]);
    gld_lds16(gAh + kt + 64 * K, &lA[0][tid * 8 + 64 * 32]);
    gld_lds16(gAl + kt,          &lA[1][tid * 8]);
    gld_lds16(gAl + kt + 64 * K, &lA[1][tid * 8 + 64 * 32]);
    gld_lds16(gBh + kt,          &lB[0][tid * 8]);
    gld_lds16(gBh + kt + 64 * K, &lB[0][tid * 8 + 64 * 32]);
    gld_lds16(gBl + kt,          &lB[1][tid * 8]);
    gld_lds16(gBl + kt + 64 * K, &lB[1][tid * 8 + 64 * 32]);
    __syncthreads();

    v8s ah[4], al[4], bh[4], bl[4];
#pragma unroll
    for (int i = 0; i < 4; ++i) {
      ah[i] = *(const v8s*)&lA[0][(wm + i * 16 + r) * 32 + quad * 8];
      al[i] = *(const v8s*)&lA[1][(wm + i * 16 + r) * 32 + quad * 8];
      bh[i] = *(const v8s*)&lB[0][(wn + i * 16 + r) * 32 + quad * 8];
      bl[i] = *(const v8s*)&lB[1][(wn + i * 16 + r) * 32 + quad * 8];
    }
#pragma unroll
    for (int i = 0; i < 4; ++i)
#pragma unroll
      for (int j = 0; j < 4; ++j) {
        acc[i][j] = __builtin_amdgcn_mfma_f32_16x16x32_bf16(ah[i], bh[j], acc[i][j], 0, 0, 0);
        acc[i][j] = __builtin_amdgcn_mfma_f32_16x16x32_bf16(ah[i], bl[j], acc[i][j], 0, 0, 0);
        acc[i][j] = __builtin_amdgcn_mfma_f32_16x16x32_bf16(al[i], bh[j], acc[i][j], 0, 0, 0);
      }
    __syncthreads();
  }

  // epilogue: C[m = quad*4+reg][n = lane&15] (verified gfx950 16x16 C/D layout)
#pragma unroll
  for (int i = 0; i < 4; ++i)
#pragma unroll
    for (int j = 0; j < 4; ++j) {
      const int gn = n0 + wn + j * 16 + r;
      const float bv = bias[gn];
#pragma unroll
      for (int q2 = 0; q2 < 4; ++q2) {
        const int gm = m0 + wm + i * 16 + quad * 4 + q2;
        outF[(size_t)gm * N + gn] = acc[i][j][q2] + bv;
      }
    }
}

// T-parallel LIF: 8 chunks of 128 steps, 64-step shadowing warm-up (state
// contracts x0.5/step -> bit-exact convergence before the chunk starts).
__global__ void __launch_bounds__(256) lif_part_kernel(const float* __restrict__ y2,
                                                       float* __restrict__ part) {
  const int idx = blockIdx.x * 256 + threadIdx.x;  // chunk*32768 + ch
  const int ch = idx & 32767, chunk = idx >> 15;
  const float* p = y2 + ((size_t)(ch >> 10) << 20) + (ch & 1023);
  const int t0 = chunk << 7;
  float v = 0.f;
  if (chunk) {  // uniform per wave (32768 % 64 == 0)
    const float* pw = p + (size_t)(t0 - 64) * 1024;
    for (int b = 0; b < 64; b += 16) {
      float x[16];
#pragma unroll
      for (int i = 0; i < 16; ++i) x[i] = pw[(size_t)(b + i) * 1024];
#pragma unroll
      for (int i = 0; i < 16; ++i) {
        v += (x[i] - v) * 0.5f;
        if (v >= 1.0f) v -= 1.0f;
      }
    }
  }
  float cnt = 0.f;
  const float* pm = p + (size_t)t0 * 1024;
  for (int b = 0; b < 128; b += 16) {
    float x[16];
#pragma unroll
    for (int i = 0; i < 16; ++i) x[i] = pm[(size_t)(b + i) * 1024];
#pragma unroll
    for (int i = 0; i < 16; ++i) {
      v += (x[i] - v) * 0.5f;              // exact reference op order
      float s = (v >= 1.0f) ? 1.0f : 0.0f;
      cnt += s;
      v -= s;
    }
  }
  part[idx] = cnt;
}

// out[b,o] = (sum_c part[c][b,:]).W_out[o,:]/1024 + b_out[o]; one wave each.
// part holds integer spike counts -> cross-chunk sum exact in any order.
__global__ void __launch_bounds__(64) head_kernel(const float* __restrict__ part,
                                                  const float* __restrict__ W_out,
                                                  const float* __restrict__ b_out,
                                                  float* __restrict__ out) {
  int blk = blockIdx.x;          // 0..319
  int b = blk / 10, o = blk % 10;
  int lane = threadIdx.x;
  const float* wr = W_out + o * 1024;
  float s = 0.f;
#pragma unroll
  for (int i = 0; i < 16; ++i) {
    const int ch = b * 1024 + lane + 64 * i;
    float p = 0.f;
#pragma unroll
    for (int c = 0; c < 8; ++c) p += part[c * 32768 + ch];
    s += p * wr[lane + 64 * i];
  }
#pragma unroll
  for (int off = 32; off > 0; off >>= 1) s += __shfl_down(s, off);
  if (lane == 0) out[b * 10 + o] = s * (1.0f / 1024.0f) + b_out[o];
}

extern "C" void kernel_launch(void* const* d_in, const int* in_sizes, int n_in,
                              void* d_out, int out_size, void* d_ws, size_t ws_size,
                              hipStream_t stream) {
  const float* x      = (const float*)d_in[0];
  const float* W_proj = (const float*)d_in[1];
  const float* b_proj = (const float*)d_in[2];
  const float* W_hid  = (const float*)d_in[3];
  const float* b_hid  = (const float*)d_in[4];
  const float* W_out  = (const float*)d_in[5];
  const float* b_out  = (const float*)d_in[6];
  float* out = (float*)d_out;

  const int M = 32768;  // B*T

  // Workspace (~270 MB): Xh[64M] | Xl[64M] | Y2 fp32 [128M] | weights | bc | part
  char* ws = (char*)d_ws;
  unsigned short* Xh   = (unsigned short*)(ws);
  unsigned short* Xl   = (unsigned short*)(ws + 67108864);
  float*          Y2   = (float*)(ws + 134217728);
  char* base = ws + 268435456;
  unsigned short* WpTh = (unsigned short*)(base);
  unsigned short* WpTl = (unsigned short*)(base + 2097152);
  unsigned short* Whh  = (unsigned short*)(base + 4194304);
  unsigned short* Whl  = (unsigned short*)(base + 6291456);
  unsigned short* Wch  = (unsigned short*)(base + 8388608);
  unsigned short* Wcl  = (unsigned short*)(base + 10485760);
  float*           bc  = (float*)(base + 12582912);
  float*          part = (float*)(base + 12582912 + 65536);

  prep_kernel<<<35072, 256, 0, stream>>>(x, W_proj, W_hid, b_proj, b_hid,
                                         Xh, Xl, WpTh, WpTl, Whh, Whl, bc);
  // Wc[g,d] = sum_h Wh[g,h] * WpT[d,h], written pre-split hi/lo
  gemm_w<<<64, 256, 0, stream>>>(Whh, Whl, WpTh, WpTl, Wch, Wcl);
  gemm_main<<<2048, 256, 0, stream>>>(Xh, Xl, Wch, Wcl, bc, Y2, M);
  lif_part_kernel<<<1024, 256, 0, stream>>>(Y2, part);
  head_kernel<<<320, 64, 0, stream>>>(part, W_out, b_out, out);
}

// Round 7
// 414.721 us; speedup vs baseline: 1.2597x; 1.1475x over previous
//
#include <hip/hip_runtime.h>
#include <stdint.h>

// SNN pipeline, algebraically fused: y2 = x @ (Wh@Wp)^T + (Wh@bp + bh), then
// T-parallel LIF scan (shadowing warm-up), pool+head.
// r7: main GEMM uses asymmetric f16 emulation: A = single f16 plane (11-bit
// mantissa), B = Wc in f16 hi/lo (22 bits) -> 2 MFMA products (was bf16 x3).
// Predicted y2 err ~2.8e-4 -> out absmax ~7e-4 (validated flip model, r6).
// Weight GEMM (Wc = Wh@Wp) stays exact-ish bf16 3-product.

typedef short v8s __attribute__((ext_vector_type(8)));
typedef _Float16 v8h __attribute__((ext_vector_type(8)));
typedef float v4f __attribute__((ext_vector_type(4)));

#define GAS __attribute__((address_space(1)))
#define LAS __attribute__((address_space(3)))

__device__ __forceinline__ unsigned short f2bf(float f) {
  unsigned int u = __float_as_uint(f);
  u += 0x7fffu + ((u >> 16) & 1u);   // round-to-nearest-even
  return (unsigned short)(u >> 16);
}
__device__ __forceinline__ float bf2f(unsigned short h) {
  return __uint_as_float(((unsigned int)h) << 16);
}
__device__ __forceinline__ unsigned short f2h(float f) {       // f32->f16 RNE
  union { _Float16 h; unsigned short u; } c;
  c.h = (_Float16)f;
  return c.u;
}
__device__ __forceinline__ float h2f(unsigned short u) {
  union { unsigned short u; _Float16 h; } c;
  c.u = u;
  return (float)c.h;
}

__device__ __forceinline__ void gld_lds16(const void* g, void* l) {
  __builtin_amdgcn_global_load_lds((const GAS void*)g, (LAS void*)l, 16, 0, 0);
}

__device__ __forceinline__ void split4(const float4 x, ushort4* h, ushort4* l) {
  h->x = f2bf(x.x); l->x = f2bf(x.x - bf2f(h->x));
  h->y = f2bf(x.y); l->y = f2bf(x.y - bf2f(h->y));
  h->z = f2bf(x.z); l->z = f2bf(x.z - bf2f(h->z));
  h->w = f2bf(x.w); l->w = f2bf(x.w - bf2f(h->w));
}

// Fused preprocessing (one launch, independent block ranges):
//  [0, 32768):      x -> f16 plane Xh           (192 MB traffic, HBM-bound)
//  [32768, 33792):  transpose+split W_proj -> WpT bf16 hi/lo
//  [33792, 34816):  split W_hid -> Wh bf16 hi/lo
//  [34816, 35072):  bc[g] = Wh[g,:].b_proj + b_hid[g]  (4 waves/block)
__global__ void __launch_bounds__(256) prep_kernel(
    const float* __restrict__ x,
    const float* __restrict__ W_proj, const float* __restrict__ W_hid,
    const float* __restrict__ b_proj, const float* __restrict__ b_hid,
    unsigned short* __restrict__ Xh,
    unsigned short* __restrict__ WpTh, unsigned short* __restrict__ WpTl,
    unsigned short* __restrict__ Whh, unsigned short* __restrict__ Whl,
    float* __restrict__ bc) {
  __shared__ float t[32][33];
  const int blk = blockIdx.x, tid = threadIdx.x;
  if (blk < 32768) {
    const int i = blk * 256 + tid;           // 8388608 float4 = 32M floats
    float4 v = ((const float4*)x)[i];
    ushort4 h;
    h.x = f2h(v.x); h.y = f2h(v.y); h.z = f2h(v.z); h.w = f2h(v.w);
    ((ushort4*)Xh)[i] = h;
  } else if (blk < 33792) {
    const int b2 = blk - 32768;
    const int tx = tid & 31, ty = tid >> 5;  // 32x8
    const int bx = b2 & 31, by = b2 >> 5;
    const int xc = bx * 32 + tx;
    const int yb = by * 32;
#pragma unroll
    for (int j = 0; j < 4; ++j) t[ty + 8 * j][tx] = W_proj[(size_t)(yb + ty + 8 * j) * 1024 + xc];
    __syncthreads();
    const int xo = yb + tx;
#pragma unroll
    for (int j = 0; j < 4; ++j) {
      const float v = t[tx][ty + 8 * j];
      const unsigned short h = f2bf(v);
      const size_t o = (size_t)(bx * 32 + ty + 8 * j) * 1024 + xo;
      WpTh[o] = h;
      WpTl[o] = f2bf(v - bf2f(h));
    }
  } else if (blk < 34816) {
    const int i = (blk - 33792) * 256 + tid; // 262144 float4 = 1M floats
    float4 v = ((const float4*)W_hid)[i];
    ushort4 h, l;
    split4(v, &h, &l);
    ((ushort4*)Whh)[i] = h;
    ((ushort4*)Whl)[i] = l;
  } else {
    const int g = (blk - 34816) * 4 + (tid >> 6);
    const int lane = tid & 63;
    const float* wr = W_hid + (size_t)g * 1024;
    float s = 0.f;
#pragma unroll
    for (int i = 0; i < 16; ++i) s += wr[lane + 64 * i] * b_proj[lane + 64 * i];
#pragma unroll
    for (int off = 32; off > 0; off >>= 1) s += __shfl_down(s, off);
    if (lane == 0) bc[g] = s + b_hid[g];
  }
}

// Weight GEMM: Wc = Wh @ WpT^T, bf16 hi/lo 3-product (near-fp32 exact),
// M=N=K=1024, 128x128 tile. Epilogue stores Wc split to f16 hi/lo (22 bits).
__global__ void __launch_bounds__(256, 2)
gemm_w(const unsigned short* __restrict__ Ah, const unsigned short* __restrict__ Al,
       const unsigned short* __restrict__ Bh, const unsigned short* __restrict__ Bl,
       unsigned short* __restrict__ outH, unsigned short* __restrict__ outL) {
  constexpr int K = 1024, N = 1024;
  __shared__ unsigned short lA[2][128 * 32];
  __shared__ unsigned short lB[2][128 * 32];

  const int tid = threadIdx.x;
  const int mt = blockIdx.x & 7, nt = blockIdx.x >> 3;  // 8x8 grid
  const int m0 = mt * 128, n0 = nt * 128;

  const int lane = tid & 63, wave = tid >> 6;
  const int wm = (wave >> 1) * 64, wn = (wave & 1) * 64;
  const int quad = lane >> 4, r = lane & 15;
  const int srow = tid >> 2, scol = (tid & 3) * 8;

  v4f acc[4][4];
#pragma unroll
  for (int i = 0; i < 4; ++i)
#pragma unroll
    for (int j = 0; j < 4; ++j) acc[i][j] = v4f{0.f, 0.f, 0.f, 0.f};

  const unsigned short* gAh = Ah + (size_t)(m0 + srow) * K + scol;
  const unsigned short* gAl = Al + (size_t)(m0 + srow) * K + scol;
  const unsigned short* gBh = Bh + (size_t)(n0 + srow) * K + scol;
  const unsigned short* gBl = Bl + (size_t)(n0 + srow) * K + scol;

  for (int kt = 0; kt < K; kt += 32) {
    gld_lds16(gAh + kt,          &lA[0][tid * 8]);
    gld_lds16(gAh + kt + 64 * K, &lA[0][tid * 8 + 64 * 32]);
    gld_lds16(gAl + kt,          &lA[1][tid * 8]);
    gld_lds16(gAl + kt + 64 * K, &lA[1][tid * 8 + 64 * 32]);
    gld_lds16(gBh + kt,          &lB[0][tid * 8]);
    gld_lds16(gBh + kt + 64 * K, &lB[0][tid * 8 + 64 * 32]);
    gld_lds16(gBl + kt,          &lB[1][tid * 8]);
    gld_lds16(gBl + kt + 64 * K, &lB[1][tid * 8 + 64 * 32]);
    __syncthreads();

    v8s ah[4], al[4], bh[4], bl[4];
#pragma unroll
    for (int i = 0; i < 4; ++i) {
      ah[i] = *(const v8s*)&lA[0][(wm + i * 16 + r) * 32 + quad * 8];
      al[i] = *(const v8s*)&lA[1][(wm + i * 16 + r) * 32 + quad * 8];
      bh[i] = *(const v8s*)&lB[0][(wn + i * 16 + r) * 32 + quad * 8];
      bl[i] = *(const v8s*)&lB[1][(wn + i * 16 + r) * 32 + quad * 8];
    }
#pragma unroll
    for (int i = 0; i < 4; ++i)
#pragma unroll
      for (int j = 0; j < 4; ++j) {
        acc[i][j] = __builtin_amdgcn_mfma_f32_16x16x32_bf16(ah[i], bh[j], acc[i][j], 0, 0, 0);
        acc[i][j] = __builtin_amdgcn_mfma_f32_16x16x32_bf16(ah[i], bl[j], acc[i][j], 0, 0, 0);
        acc[i][j] = __builtin_amdgcn_mfma_f32_16x16x32_bf16(al[i], bh[j], acc[i][j], 0, 0, 0);
      }
    __syncthreads();
  }

#pragma unroll
  for (int i = 0; i < 4; ++i)
#pragma unroll
    for (int j = 0; j < 4; ++j) {
      const int gn = n0 + wn + j * 16 + r;
#pragma unroll
      for (int q2 = 0; q2 < 4; ++q2) {
        const int gm = m0 + wm + i * 16 + quad * 4 + q2;
        const float y = acc[i][j][q2];
        const unsigned short h = f2h(y);           // f16 hi
        const size_t o = (size_t)gm * N + gn;
        outH[o] = h;
        outL[o] = f2h(y - h2f(h));                 // f16 lo
      }
    }
}

// Main GEMM: Y2 = Xf16 @ Wc^T + bc, A single f16 plane, B f16 hi/lo,
// 2 MFMA products (16x16x32_f16). 128x128 tile, BK=32, 4 waves 2x2 of 64x64,
// all staging async gld_lds. XCD swizzle: 8 consecutive blocks share an
// A-band across the 8 XCDs.
__global__ void __launch_bounds__(256, 4)
gemm_main(const unsigned short* __restrict__ Ah,
          const unsigned short* __restrict__ Bh, const unsigned short* __restrict__ Bl,
          const float* __restrict__ bias, float* __restrict__ outF, int M) {
  constexpr int K = 1024, N = 1024;
  __shared__ unsigned short lA[128 * 32];     // 8 KB
  __shared__ unsigned short lB[2][128 * 32];  // 16 KB

  const int tid = threadIdx.x;
  const int band = (M >> 7) >> 3;            // 32 for M=32768
  const int c = blockIdx.x & 7, idx = blockIdx.x >> 3;
  const int mt = c * band + (idx >> 3), nt = idx & 7;
  const int m0 = mt * 128, n0 = nt * 128;

  const int lane = tid & 63, wave = tid >> 6;
  const int wm = (wave >> 1) * 64, wn = (wave & 1) * 64;
  const int quad = lane >> 4, r = lane & 15;
  const int srow = tid >> 2, scol = (tid & 3) * 8;

  v4f acc[4][4];
#pragma unroll
  for (int i = 0; i < 4; ++i)
#pragma unroll
    for (int j = 0; j < 4; ++j) acc[i][j] = v4f{0.f, 0.f, 0.f, 0.f};

  const unsigned short* gAh = Ah + (size_t)(m0 + srow) * K + scol;
  const unsigned short* gBh = Bh + (size_t)(n0 + srow) * K + scol;
  const unsigned short* gBl = Bl + (size_t)(n0 + srow) * K + scol;

  for (int kt = 0; kt < K; kt += 32) {
    gld_lds16(gAh + kt,          &lA[tid * 8]);
    gld_lds16(gAh + kt + 64 * K, &lA[tid * 8 + 64 * 32]);
    gld_lds16(gBh + kt,          &lB[0][tid * 8]);
    gld_lds16(gBh + kt + 64 * K, &lB[0][tid * 8 + 64 * 32]);
    gld_lds16(gBl + kt,          &lB[1][tid * 8]);
    gld_lds16(gBl + kt + 64 * K, &lB[1][tid * 8 + 64 * 32]);
    __syncthreads();

    v8h ah[4], bh[4], bl[4];
#pragma unroll
    for (int i = 0; i < 4; ++i) {
      ah[i] = *(const v8h*)&lA[(wm + i * 16 + r) * 32 + quad * 8];
      bh[i] = *(const v8h*)&lB[0][(wn + i * 16 + r) * 32 + quad * 8];
      bl[i] = *(const v8h*)&lB[1][(wn + i * 16 + r) * 32 + quad * 8];
    }
#pragma unroll
    for (int i = 0; i < 4; ++i)
#pragma unroll
      for (int j = 0; j < 4; ++j) {
        acc[i][j] = __builtin_amdgcn_mfma_f32_16x16x32_f16(ah[i], bh[j], acc[i][j], 0, 0, 0);
        acc[i][j] = __builtin_amdgcn_mfma_f32_16x16x32_f16(ah[i], bl[j], acc[i][j], 0, 0, 0);
      }
    __syncthreads();
  }

  // epilogue: C[m = quad*4+reg][n = lane&15] (verified gfx950 16x16 C/D layout)
#pragma unroll
  for (int i = 0; i < 4; ++i)
#pragma unroll
    for (int j = 0; j < 4; ++j) {
      const int gn = n0 + wn + j * 16 + r;
      const float bv = bias[gn];
#pragma unroll
      for (int q2 = 0; q2 < 4; ++q2) {
        const int gm = m0 + wm + i * 16 + quad * 4 + q2;
        outF[(size_t)gm * N + gn] = acc[i][j][q2] + bv;
      }
    }
}

// T-parallel LIF: 8 chunks of 128 steps, 64-step shadowing warm-up (state
// contracts x0.5/step -> bit-exact convergence before the chunk starts).
__global__ void __launch_bounds__(256) lif_part_kernel(const float* __restrict__ y2,
                                                       float* __restrict__ part) {
  const int idx = blockIdx.x * 256 + threadIdx.x;  // chunk*32768 + ch
  const int ch = idx & 32767, chunk = idx >> 15;
  const float* p = y2 + ((size_t)(ch >> 10) << 20) + (ch & 1023);
  const int t0 = chunk << 7;
  float v = 0.f;
  if (chunk) {  // uniform per wave (32768 % 64 == 0)
    const float* pw = p + (size_t)(t0 - 64) * 1024;
    for (int b = 0; b < 64; b += 16) {
      float x[16];
#pragma unroll
      for (int i = 0; i < 16; ++i) x[i] = pw[(size_t)(b + i) * 1024];
#pragma unroll
      for (int i = 0; i < 16; ++i) {
        v += (x[i] - v) * 0.5f;
        if (v >= 1.0f) v -= 1.0f;
      }
    }
  }
  float cnt = 0.f;
  const float* pm = p + (size_t)t0 * 1024;
  for (int b = 0; b < 128; b += 16) {
    float x[16];
#pragma unroll
    for (int i = 0; i < 16; ++i) x[i] = pm[(size_t)(b + i) * 1024];
#pragma unroll
    for (int i = 0; i < 16; ++i) {
      v += (x[i] - v) * 0.5f;              // exact reference op order
      float s = (v >= 1.0f) ? 1.0f : 0.0f;
      cnt += s;
      v -= s;
    }
  }
  part[idx] = cnt;
}

// out[b,o] = (sum_c part[c][b,:]).W_out[o,:]/1024 + b_out[o]; one wave each.
// part holds integer spike counts -> cross-chunk sum exact in any order.
__global__ void __launch_bounds__(64) head_kernel(const float* __restrict__ part,
                                                  const float* __restrict__ W_out,
                                                  const float* __restrict__ b_out,
                                                  float* __restrict__ out) {
  int blk = blockIdx.x;          // 0..319
  int b = blk / 10, o = blk % 10;
  int lane = threadIdx.x;
  const float* wr = W_out + o * 1024;
  float s = 0.f;
#pragma unroll
  for (int i = 0; i < 16; ++i) {
    const int ch = b * 1024 + lane + 64 * i;
    float p = 0.f;
#pragma unroll
    for (int c = 0; c < 8; ++c) p += part[c * 32768 + ch];
    s += p * wr[lane + 64 * i];
  }
#pragma unroll
  for (int off = 32; off > 0; off >>= 1) s += __shfl_down(s, off);
  if (lane == 0) out[b * 10 + o] = s * (1.0f / 1024.0f) + b_out[o];
}

extern "C" void kernel_launch(void* const* d_in, const int* in_sizes, int n_in,
                              void* d_out, int out_size, void* d_ws, size_t ws_size,
                              hipStream_t stream) {
  const float* x      = (const float*)d_in[0];
  const float* W_proj = (const float*)d_in[1];
  const float* b_proj = (const float*)d_in[2];
  const float* W_hid  = (const float*)d_in[3];
  const float* b_hid  = (const float*)d_in[4];
  const float* W_out  = (const float*)d_in[5];
  const float* b_out  = (const float*)d_in[6];
  float* out = (float*)d_out;

  const int M = 32768;  // B*T

  // Workspace (~207 MB): Xh f16 [64M] | Y2 fp32 [128M] | weights | bc | part
  char* ws = (char*)d_ws;
  unsigned short* Xh   = (unsigned short*)(ws);
  float*          Y2   = (float*)(ws + 67108864);
  char* base = ws + 201326592;
  unsigned short* WpTh = (unsigned short*)(base);             // bf16
  unsigned short* WpTl = (unsigned short*)(base + 2097152);
  unsigned short* Whh  = (unsigned short*)(base + 4194304);
  unsigned short* Whl  = (unsigned short*)(base + 6291456);
  unsigned short* Wch  = (unsigned short*)(base + 8388608);   // f16
  unsigned short* Wcl  = (unsigned short*)(base + 10485760);
  float*           bc  = (float*)(base + 12582912);
  float*          part = (float*)(base + 12582912 + 65536);

  prep_kernel<<<35072, 256, 0, stream>>>(x, W_proj, W_hid, b_proj, b_hid,
                                         Xh, WpTh, WpTl, Whh, Whl, bc);
  // Wc[g,d] = sum_h Wh[g,h] * WpT[d,h], stored as f16 hi/lo
  gemm_w<<<64, 256, 0, stream>>>(Whh, Whl, WpTh, WpTl, Wch, Wcl);
  gemm_main<<<2048, 256, 0, stream>>>(Xh, Wch, Wcl, bc, Y2, M);
  lif_part_kernel<<<1024, 256, 0, stream>>>(Y2, part);
  head_kernel<<<320, 64, 0, stream>>>(part, W_out, b_out, out);
}

// Round 8
// 400.843 us; speedup vs baseline: 1.3033x; 1.0346x over previous
//
#include <hip/hip_runtime.h>
#include <stdint.h>

// SNN pipeline, algebraically fused: y2 = x @ (Wh@Wp)^T + (Wh@bp + bh), then
// T-parallel LIF scan (shadowing warm-up), pool+head.
// r7: main GEMM = asymmetric f16 emulation (A single f16 plane, B f16 hi/lo,
//     2 MFMA products). r8: Y2 intermediate stored f16 (halves GEMM-out +
//     LIF-in traffic; quant err ~1.2e-4 << 2.8e-4 GEMM err), warm-up 64->32.

typedef short v8s __attribute__((ext_vector_type(8)));
typedef _Float16 v8h __attribute__((ext_vector_type(8)));
typedef float v4f __attribute__((ext_vector_type(4)));

#define GAS __attribute__((address_space(1)))
#define LAS __attribute__((address_space(3)))

__device__ __forceinline__ unsigned short f2bf(float f) {
  unsigned int u = __float_as_uint(f);
  u += 0x7fffu + ((u >> 16) & 1u);   // round-to-nearest-even
  return (unsigned short)(u >> 16);
}
__device__ __forceinline__ float bf2f(unsigned short h) {
  return __uint_as_float(((unsigned int)h) << 16);
}
__device__ __forceinline__ unsigned short f2h(float f) {       // f32->f16 RNE
  union { _Float16 h; unsigned short u; } c;
  c.h = (_Float16)f;
  return c.u;
}
__device__ __forceinline__ float h2f(unsigned short u) {
  union { unsigned short u; _Float16 h; } c;
  c.u = u;
  return (float)c.h;
}

__device__ __forceinline__ void gld_lds16(const void* g, void* l) {
  __builtin_amdgcn_global_load_lds((const GAS void*)g, (LAS void*)l, 16, 0, 0);
}

__device__ __forceinline__ void split4(const float4 x, ushort4* h, ushort4* l) {
  h->x = f2bf(x.x); l->x = f2bf(x.x - bf2f(h->x));
  h->y = f2bf(x.y); l->y = f2bf(x.y - bf2f(h->y));
  h->z = f2bf(x.z); l->z = f2bf(x.z - bf2f(h->z));
  h->w = f2bf(x.w); l->w = f2bf(x.w - bf2f(h->w));
}

// Fused preprocessing (one launch, independent block ranges):
//  [0, 32768):      x -> f16 plane Xh           (192 MB traffic, HBM-bound)
//  [32768, 33792):  transpose+split W_proj -> WpT bf16 hi/lo
//  [33792, 34816):  split W_hid -> Wh bf16 hi/lo
//  [34816, 35072):  bc[g] = Wh[g,:].b_proj + b_hid[g]  (4 waves/block)
__global__ void __launch_bounds__(256) prep_kernel(
    const float* __restrict__ x,
    const float* __restrict__ W_proj, const float* __restrict__ W_hid,
    const float* __restrict__ b_proj, const float* __restrict__ b_hid,
    unsigned short* __restrict__ Xh,
    unsigned short* __restrict__ WpTh, unsigned short* __restrict__ WpTl,
    unsigned short* __restrict__ Whh, unsigned short* __restrict__ Whl,
    float* __restrict__ bc) {
  __shared__ float t[32][33];
  const int blk = blockIdx.x, tid = threadIdx.x;
  if (blk < 32768) {
    const int i = blk * 256 + tid;           // 8388608 float4 = 32M floats
    float4 v = ((const float4*)x)[i];
    ushort4 h;
    h.x = f2h(v.x); h.y = f2h(v.y); h.z = f2h(v.z); h.w = f2h(v.w);
    ((ushort4*)Xh)[i] = h;
  } else if (blk < 33792) {
    const int b2 = blk - 32768;
    const int tx = tid & 31, ty = tid >> 5;  // 32x8
    const int bx = b2 & 31, by = b2 >> 5;
    const int xc = bx * 32 + tx;
    const int yb = by * 32;
#pragma unroll
    for (int j = 0; j < 4; ++j) t[ty + 8 * j][tx] = W_proj[(size_t)(yb + ty + 8 * j) * 1024 + xc];
    __syncthreads();
    const int xo = yb + tx;
#pragma unroll
    for (int j = 0; j < 4; ++j) {
      const float v = t[tx][ty + 8 * j];
      const unsigned short h = f2bf(v);
      const size_t o = (size_t)(bx * 32 + ty + 8 * j) * 1024 + xo;
      WpTh[o] = h;
      WpTl[o] = f2bf(v - bf2f(h));
    }
  } else if (blk < 34816) {
    const int i = (blk - 33792) * 256 + tid; // 262144 float4 = 1M floats
    float4 v = ((const float4*)W_hid)[i];
    ushort4 h, l;
    split4(v, &h, &l);
    ((ushort4*)Whh)[i] = h;
    ((ushort4*)Whl)[i] = l;
  } else {
    const int g = (blk - 34816) * 4 + (tid >> 6);
    const int lane = tid & 63;
    const float* wr = W_hid + (size_t)g * 1024;
    float s = 0.f;
#pragma unroll
    for (int i = 0; i < 16; ++i) s += wr[lane + 64 * i] * b_proj[lane + 64 * i];
#pragma unroll
    for (int off = 32; off > 0; off >>= 1) s += __shfl_down(s, off);
    if (lane == 0) bc[g] = s + b_hid[g];
  }
}

// Weight GEMM: Wc = Wh @ WpT^T, bf16 hi/lo 3-product (near-fp32 exact),
// M=N=K=1024, 128x128 tile. Epilogue stores Wc split to f16 hi/lo (22 bits).
__global__ void __launch_bounds__(256, 2)
gemm_w(const unsigned short* __restrict__ Ah, const unsigned short* __restrict__ Al,
       const unsigned short* __restrict__ Bh, const unsigned short* __restrict__ Bl,
       unsigned short* __restrict__ outH, unsigned short* __restrict__ outL) {
  constexpr int K = 1024, N = 1024;
  __shared__ unsigned short lA[2][128 * 32];
  __shared__ unsigned short lB[2][128 * 32];

  const int tid = threadIdx.x;
  const int mt = blockIdx.x & 7, nt = blockIdx.x >> 3;  // 8x8 grid
  const int m0 = mt * 128, n0 = nt * 128;

  const int lane = tid & 63, wave = tid >> 6;
  const int wm = (wave >> 1) * 64, wn = (wave & 1) * 64;
  const int quad = lane >> 4, r = lane & 15;
  const int srow = tid >> 2, scol = (tid & 3) * 8;

  v4f acc[4][4];
#pragma unroll
  for (int i = 0; i < 4; ++i)
#pragma unroll
    for (int j = 0; j < 4; ++j) acc[i][j] = v4f{0.f, 0.f, 0.f, 0.f};

  const unsigned short* gAh = Ah + (size_t)(m0 + srow) * K + scol;
  const unsigned short* gAl = Al + (size_t)(m0 + srow) * K + scol;
  const unsigned short* gBh = Bh + (size_t)(n0 + srow) * K + scol;
  const unsigned short* gBl = Bl + (size_t)(n0 + srow) * K + scol;

  for (int kt = 0; kt < K; kt += 32) {
    gld_lds16(gAh + kt,          &lA[0][tid * 8]);
    gld_lds16(gAh + kt + 64 * K, &lA[0][tid * 8 + 64 * 32]);
    gld_lds16(gAl + kt,          &lA[1][tid * 8]);
    gld_lds16(gAl + kt + 64 * K, &lA[1][tid * 8 + 64 * 32]);
    gld_lds16(gBh + kt,          &lB[0][tid * 8]);
    gld_lds16(gBh + kt + 64 * K, &lB[0][tid * 8 + 64 * 32]);
    gld_lds16(gBl + kt,          &lB[1][tid * 8]);
    gld_lds16(gBl + kt + 64 * K, &lB[1][tid * 8 + 64 * 32]);
    __syncthreads();

    v8s ah[4], al[4], bh[4], bl[4];
#pragma unroll
    for (int i = 0; i < 4; ++i) {
      ah[i] = *(const v8s*)&lA[0][(wm + i * 16 + r) * 32 + quad * 8];
      al[i] = *(const v8s*)&lA[1][(wm + i * 16 + r) * 32 + quad * 8];
      bh[i] = *(const v8s*)&lB[0][(wn + i * 16 + r) * 32 + quad * 8];
      bl[i] = *(const v8s*)&lB[1][(wn + i * 16 + r) * 32 + quad * 8];
    }
#pragma unroll
    for (int i = 0; i < 4; ++i)
#pragma unroll
      for (int j = 0; j < 4; ++j) {
        acc[i][j] = __builtin_amdgcn_mfma_f32_16x16x32_bf16(ah[i], bh[j], acc[i][j], 0, 0, 0);
        acc[i][j] = __builtin_amdgcn_mfma_f32_16x16x32_bf16(ah[i], bl[j], acc[i][j], 0, 0, 0);
        acc[i][j] = __builtin_amdgcn_mfma_f32_16x16x32_bf16(al[i], bh[j], acc[i][j], 0, 0, 0);
      }
    __syncthreads();
  }

#pragma unroll
  for (int i = 0; i < 4; ++i)
#pragma unroll
    for (int j = 0; j < 4; ++j) {
      const int gn = n0 + wn + j * 16 + r;
#pragma unroll
      for (int q2 = 0; q2 < 4; ++q2) {
        const int gm = m0 + wm + i * 16 + quad * 4 + q2;
        const float y = acc[i][j][q2];
        const unsigned short h = f2h(y);           // f16 hi
        const size_t o = (size_t)gm * N + gn;
        outH[o] = h;
        outL[o] = f2h(y - h2f(h));                 // f16 lo
      }
    }
}

// Main GEMM: Y2(f16) = Xf16 @ Wc^T + bc, A single f16 plane, B f16 hi/lo,
// 2 MFMA products (16x16x32_f16). 128x128 tile, BK=32, 4 waves 2x2 of 64x64,
// all staging async gld_lds. XCD swizzle: 8 consecutive blocks share an
// A-band across the 8 XCDs.
__global__ void __launch_bounds__(256, 4)
gemm_main(const unsigned short* __restrict__ Ah,
          const unsigned short* __restrict__ Bh, const unsigned short* __restrict__ Bl,
          const float* __restrict__ bias, unsigned short* __restrict__ outH, int M) {
  constexpr int K = 1024, N = 1024;
  __shared__ unsigned short lA[128 * 32];     // 8 KB
  __shared__ unsigned short lB[2][128 * 32];  // 16 KB

  const int tid = threadIdx.x;
  const int band = (M >> 7) >> 3;            // 32 for M=32768
  const int c = blockIdx.x & 7, idx = blockIdx.x >> 3;
  const int mt = c * band + (idx >> 3), nt = idx & 7;
  const int m0 = mt * 128, n0 = nt * 128;

  const int lane = tid & 63, wave = tid >> 6;
  const int wm = (wave >> 1) * 64, wn = (wave & 1) * 64;
  const int quad = lane >> 4, r = lane & 15;
  const int srow = tid >> 2, scol = (tid & 3) * 8;

  v4f acc[4][4];
#pragma unroll
  for (int i = 0; i < 4; ++i)
#pragma unroll
    for (int j = 0; j < 4; ++j) acc[i][j] = v4f{0.f, 0.f, 0.f, 0.f};

  const unsigned short* gAh = Ah + (size_t)(m0 + srow) * K + scol;
  const unsigned short* gBh = Bh + (size_t)(n0 + srow) * K + scol;
  const unsigned short* gBl = Bl + (size_t)(n0 + srow) * K + scol;

  for (int kt = 0; kt < K; kt += 32) {
    gld_lds16(gAh + kt,          &lA[tid * 8]);
    gld_lds16(gAh + kt + 64 * K, &lA[tid * 8 + 64 * 32]);
    gld_lds16(gBh + kt,          &lB[0][tid * 8]);
    gld_lds16(gBh + kt + 64 * K, &lB[0][tid * 8 + 64 * 32]);
    gld_lds16(gBl + kt,          &lB[1][tid * 8]);
    gld_lds16(gBl + kt + 64 * K, &lB[1][tid * 8 + 64 * 32]);
    __syncthreads();

    v8h ah[4], bh[4], bl[4];
#pragma unroll
    for (int i = 0; i < 4; ++i) {
      ah[i] = *(const v8h*)&lA[(wm + i * 16 + r) * 32 + quad * 8];
      bh[i] = *(const v8h*)&lB[0][(wn + i * 16 + r) * 32 + quad * 8];
      bl[i] = *(const v8h*)&lB[1][(wn + i * 16 + r) * 32 + quad * 8];
    }
#pragma unroll
    for (int i = 0; i < 4; ++i)
#pragma unroll
      for (int j = 0; j < 4; ++j) {
        acc[i][j] = __builtin_amdgcn_mfma_f32_16x16x32_f16(ah[i], bh[j], acc[i][j], 0, 0, 0);
        acc[i][j] = __builtin_amdgcn_mfma_f32_16x16x32_f16(ah[i], bl[j], acc[i][j], 0, 0, 0);
      }
    __syncthreads();
  }

  // epilogue: C[m = quad*4+reg][n = lane&15]; store f16
#pragma unroll
  for (int i = 0; i < 4; ++i)
#pragma unroll
    for (int j = 0; j < 4; ++j) {
      const int gn = n0 + wn + j * 16 + r;
      const float bv = bias[gn];
#pragma unroll
      for (int q2 = 0; q2 < 4; ++q2) {
        const int gm = m0 + wm + i * 16 + quad * 4 + q2;
        outH[(size_t)gm * N + gn] = f2h(acc[i][j][q2] + bv);
      }
    }
}

// T-parallel LIF over f16 y2: 8 chunks of 128 steps, 32-step shadowing
// warm-up (state contracts x0.5/step; 2^-32 residual ~1e-9 -> no flips).
__global__ void __launch_bounds__(256) lif_part_kernel(const unsigned short* __restrict__ y2,
                                                       float* __restrict__ part) {
  const int idx = blockIdx.x * 256 + threadIdx.x;  // chunk*32768 + ch
  const int ch = idx & 32767, chunk = idx >> 15;
  const unsigned short* p = y2 + ((size_t)(ch >> 10) << 20) + (ch & 1023);
  const int t0 = chunk << 7;
  float v = 0.f;
  if (chunk) {  // uniform per wave (32768 % 64 == 0)
    const unsigned short* pw = p + (size_t)(t0 - 32) * 1024;
    for (int b = 0; b < 32; b += 16) {
      float x[16];
#pragma unroll
      for (int i = 0; i < 16; ++i) x[i] = h2f(pw[(size_t)(b + i) * 1024]);
#pragma unroll
      for (int i = 0; i < 16; ++i) {
        v += (x[i] - v) * 0.5f;
        if (v >= 1.0f) v -= 1.0f;
      }
    }
  }
  float cnt = 0.f;
  const unsigned short* pm = p + (size_t)t0 * 1024;
  for (int b = 0; b < 128; b += 16) {
    float x[16];
#pragma unroll
    for (int i = 0; i < 16; ++i) x[i] = h2f(pm[(size_t)(b + i) * 1024]);
#pragma unroll
    for (int i = 0; i < 16; ++i) {
      v += (x[i] - v) * 0.5f;              // exact reference op order
      float s = (v >= 1.0f) ? 1.0f : 0.0f;
      cnt += s;
      v -= s;
    }
  }
  part[idx] = cnt;
}

// out[b,o] = (sum_c part[c][b,:]).W_out[o,:]/1024 + b_out[o]; one wave each.
// part holds integer spike counts -> cross-chunk sum exact in any order.
__global__ void __launch_bounds__(64) head_kernel(const float* __restrict__ part,
                                                  const float* __restrict__ W_out,
                                                  const float* __restrict__ b_out,
                                                  float* __restrict__ out) {
  int blk = blockIdx.x;          // 0..319
  int b = blk / 10, o = blk % 10;
  int lane = threadIdx.x;
  const float* wr = W_out + o * 1024;
  float s = 0.f;
#pragma unroll
  for (int i = 0; i < 16; ++i) {
    const int ch = b * 1024 + lane + 64 * i;
    float p = 0.f;
#pragma unroll
    for (int c = 0; c < 8; ++c) p += part[c * 32768 + ch];
    s += p * wr[lane + 64 * i];
  }
#pragma unroll
  for (int off = 32; off > 0; off >>= 1) s += __shfl_down(s, off);
  if (lane == 0) out[b * 10 + o] = s * (1.0f / 1024.0f) + b_out[o];
}

extern "C" void kernel_launch(void* const* d_in, const int* in_sizes, int n_in,
                              void* d_out, int out_size, void* d_ws, size_t ws_size,
                              hipStream_t stream) {
  const float* x      = (const float*)d_in[0];
  const float* W_proj = (const float*)d_in[1];
  const float* b_proj = (const float*)d_in[2];
  const float* W_hid  = (const float*)d_in[3];
  const float* b_hid  = (const float*)d_in[4];
  const float* W_out  = (const float*)d_in[5];
  const float* b_out  = (const float*)d_in[6];
  float* out = (float*)d_out;

  const int M = 32768;  // B*T

  // Workspace (~143 MB): Xh f16 [64M] | Y2 f16 [64M] | weights | bc | part
  char* ws = (char*)d_ws;
  unsigned short* Xh   = (unsigned short*)(ws);
  unsigned short* Y2   = (unsigned short*)(ws + 67108864);
  char* base = ws + 134217728;
  unsigned short* WpTh = (unsigned short*)(base);             // bf16
  unsigned short* WpTl = (unsigned short*)(base + 2097152);
  unsigned short* Whh  = (unsigned short*)(base + 4194304);
  unsigned short* Whl  = (unsigned short*)(base + 6291456);
  unsigned short* Wch  = (unsigned short*)(base + 8388608);   // f16
  unsigned short* Wcl  = (unsigned short*)(base + 10485760);
  float*           bc  = (float*)(base + 12582912);
  float*          part = (float*)(base + 12582912 + 65536);

  prep_kernel<<<35072, 256, 0, stream>>>(x, W_proj, W_hid, b_proj, b_hid,
                                         Xh, WpTh, WpTl, Whh, Whl, bc);
  // Wc[g,d] = sum_h Wh[g,h] * WpT[d,h], stored as f16 hi/lo
  gemm_w<<<64, 256, 0, stream>>>(Whh, Whl, WpTh, WpTl, Wch, Wcl);
  gemm_main<<<2048, 256, 0, stream>>>(Xh, Wch, Wcl, bc, Y2, M);
  lif_part_kernel<<<1024, 256, 0, stream>>>(Y2, part);
  head_kernel<<<320, 64, 0, stream>>>(part, W_out, b_out, out);
}